// Round 9
// baseline (435.728 us; speedup 1.0000x reference)
//
#include <hip/hip_runtime.h>
#include <hip/hip_bf16.h>

typedef unsigned short u16;
typedef float f32x4 __attribute__((ext_vector_type(4)));
typedef __bf16 bf16x8 __attribute__((ext_vector_type(8)));

#define BB 4
#define SS 2048
#define DD 1024
#define HH 16
#define HDD 64
#define MM (BB*SS)   // 8192

__device__ __forceinline__ u16 f2bf(float f){
    union { float f; unsigned int i; } v; v.f = f;
    unsigned int i = v.i;
    return (u16)((i + 0x7FFFu + ((i >> 16) & 1u)) >> 16);
}
__device__ __forceinline__ ushort2 pk2(float a, float b){
    union { __hip_bfloat162 h; ushort2 u; } v;
    float2 t; t.x = a; t.y = b;
    v.h = __float22bfloat162_rn(t);
    return v.u;
}
__device__ __forceinline__ ushort4 pk4(float a, float b, float c, float d){
    ushort2 lo = pk2(a, b), hi = pk2(c, d);
    ushort4 r; r.x = lo.x; r.y = lo.y; r.z = hi.x; r.w = hi.y;
    return r;
}
__device__ __forceinline__ void gl2lds16(const void* g, void* l){
    __builtin_amdgcn_global_load_lds(
        (const __attribute__((address_space(1))) void*)g,
        (__attribute__((address_space(3))) void*)l, 16, 0, 0);
}

// ---------------- x fp32 -> bf16 pre-convert ----------------
__global__ __launch_bounds__(256) void cvt_k(const float* __restrict__ src,
                                             u16* __restrict__ dst)
{
    const size_t i = ((size_t)blockIdx.x * 256 + threadIdx.x) * 8;
    const float4 a = *(const float4*)&src[i];
    const float4 b = *(const float4*)&src[i + 4];
    ushort4 lo = pk4(a.x, a.y, a.z, a.w);
    ushort4 hi = pk4(b.x, b.y, b.z, b.w);
    uint4 o;
    o.x = (unsigned)lo.x | ((unsigned)lo.y << 16);
    o.y = (unsigned)lo.z | ((unsigned)lo.w << 16);
    o.z = (unsigned)hi.x | ((unsigned)hi.y << 16);
    o.w = (unsigned)hi.z | ((unsigned)hi.w << 16);
    *(uint4*)&dst[i] = o;
}

// ---------------- GEMM core: C[128,128] tile of A_bf16[M,K] @ W_f32[N,K]^T ----------------
// R9: A-operand staged via global_load_lds width=16 (async, no VGPR round-trip);
// W stays explicit load + packed cvt (fp32 source needs conversion).
__device__ __forceinline__ void gemm_core(const u16* __restrict__ A,
                                          const float* __restrict__ W,
                                          f32x4 (&acc)[4][4],
                                          u16* At, u16* Bt,
                                          int m0, int n0, int tid)
{
    const int lane = tid & 63, w = tid >> 6;
    const int quad = lane >> 4, l15 = lane & 15;
    const int wm = w >> 1, wn = w & 1;
    const int arow = lane >> 2;          // 0..15 within chunk
    const int acol = (lane & 3) * 8;     // element offset (16B)

    for (int k0 = 0; k0 < DD; k0 += 32) {
        __syncthreads();
        // A: async direct-to-LDS, chunk ch = 16 rows x 32 elems, lane-linear
        #pragma unroll
        for (int c = 0; c < 2; ++c) {
            const int ch = w * 2 + c;     // wave-uniform
            gl2lds16(&A[(size_t)(m0 + ch * 16 + arow) * DD + k0 + acol], &At[ch * 512]);
        }
        // W: explicit + convert
        #pragma unroll
        for (int it = 0; it < 2; ++it) {
            const int c = tid + it * 256;
            const int row = c >> 2, cc = (c & 3) * 8;
            const size_t woff = (size_t)(n0 + row) * DD + k0 + cc;
            const float4 u0 = *(const float4*)&W[woff];
            const float4 u1 = *(const float4*)&W[woff + 4];
            ushort4 lo = pk4(u0.x, u0.y, u0.z, u0.w);
            ushort4 hi = pk4(u1.x, u1.y, u1.z, u1.w);
            uint4 o;
            o.x = (unsigned)lo.x | ((unsigned)lo.y << 16);
            o.y = (unsigned)lo.z | ((unsigned)lo.w << 16);
            o.z = (unsigned)hi.x | ((unsigned)hi.y << 16);
            o.w = (unsigned)hi.z | ((unsigned)hi.w << 16);
            *(uint4*)&Bt[row * 32 + cc] = o;
        }
        __syncthreads();   // compiler drains vmcnt (incl. global_load_lds) + lgkm here
        bf16x8 af[4], bfr[4];
        #pragma unroll
        for (int i = 0; i < 4; ++i)
            af[i] = *(const bf16x8*)&At[(wm * 64 + i * 16 + l15) * 32 + quad * 8];
        #pragma unroll
        for (int j = 0; j < 4; ++j)
            bfr[j] = *(const bf16x8*)&Bt[(wn * 64 + j * 16 + l15) * 32 + quad * 8];
        #pragma unroll
        for (int i = 0; i < 4; ++i)
            #pragma unroll
            for (int j = 0; j < 4; ++j)
                acc[i][j] = __builtin_amdgcn_mfma_f32_16x16x32_bf16(af[i], bfr[j], acc[i][j], 0, 0, 0);
    }
}

// QKV projection: z selects q/k/v; output scattered to [B,H,S,HD] (bf16)
__global__ __launch_bounds__(256, 4) void gemm_qkv_k(
    const u16* __restrict__ x,
    const float* __restrict__ Wq, const float* __restrict__ bq,
    const float* __restrict__ Wk, const float* __restrict__ bk,
    const float* __restrict__ Wv, const float* __restrict__ bv,
    u16* __restrict__ Q, u16* __restrict__ K, u16* __restrict__ V)
{
    __shared__ alignas(16) u16 At[128 * 32];
    __shared__ alignas(16) u16 Bt[128 * 32];
    const int tid = threadIdx.x, lane = tid & 63, w = tid >> 6;
    const int quad = lane >> 4, l15 = lane & 15;
    const int wm = w >> 1, wn = w & 1;
    const int z = blockIdx.z;
    const float* Wm = z == 0 ? Wq : (z == 1 ? Wk : Wv);
    const float* bias = z == 0 ? bq : (z == 1 ? bk : bv);
    u16* Out = z == 0 ? Q : (z == 1 ? K : V);
    const int m0 = blockIdx.x * 128, n0 = blockIdx.y * 128;

    f32x4 acc[4][4];
    #pragma unroll
    for (int i = 0; i < 4; ++i)
        #pragma unroll
        for (int j = 0; j < 4; ++j) acc[i][j] = (f32x4)(0.0f);

    gemm_core(x, Wm, acc, At, Bt, m0, n0, tid);

    float bs[4];
    #pragma unroll
    for (int j = 0; j < 4; ++j) bs[j] = bias[n0 + wn * 64 + j * 16 + l15];

    const int b = m0 / SS;
    const int h = (n0 + wn * 64) / HDD;
    const size_t base = ((size_t)(b * HH + h)) * SS * HDD;
    #pragma unroll
    for (int i = 0; i < 4; ++i) {
        #pragma unroll
        for (int r = 0; r < 4; ++r) {
            const int s = (m0 % SS) + wm * 64 + i * 16 + quad * 4 + r;
            #pragma unroll
            for (int j = 0; j < 4; ++j) {
                const int hd = j * 16 + l15;
                Out[base + (size_t)s * HDD + hd] = f2bf(acc[i][j][r] + bs[j]);
            }
        }
    }
}

// Output projection: A bf16 [M,K], Wo fp32, out fp32 [M,N]
__global__ __launch_bounds__(256, 4) void gemm_out_k(
    const u16* __restrict__ A, const float* __restrict__ Wo,
    const float* __restrict__ bo, float* __restrict__ Out)
{
    __shared__ alignas(16) u16 At[128 * 32];
    __shared__ alignas(16) u16 Bt[128 * 32];
    const int tid = threadIdx.x, lane = tid & 63, w = tid >> 6;
    const int quad = lane >> 4, l15 = lane & 15;
    const int wm = w >> 1, wn = w & 1;
    const int m0 = blockIdx.x * 128, n0 = blockIdx.y * 128;

    f32x4 acc[4][4];
    #pragma unroll
    for (int i = 0; i < 4; ++i)
        #pragma unroll
        for (int j = 0; j < 4; ++j) acc[i][j] = (f32x4)(0.0f);

    gemm_core(A, Wo, acc, At, Bt, m0, n0, tid);

    float bs[4];
    #pragma unroll
    for (int j = 0; j < 4; ++j) bs[j] = bo[n0 + wn * 64 + j * 16 + l15];

    #pragma unroll
    for (int i = 0; i < 4; ++i) {
        #pragma unroll
        for (int r = 0; r < 4; ++r) {
            const int m = m0 + wm * 64 + i * 16 + quad * 4 + r;
            #pragma unroll
            for (int j = 0; j < 4; ++j) {
                const int n = n0 + wn * 64 + j * 16 + l15;
                Out[(size_t)m * DD + n] = acc[i][j][r] + bs[j];
            }
        }
    }
}

// ---------------- Flash attention, S^T/O^T formulation ----------------
// R9: grid reverted to R6 layout (x=qt reversed, y=bh) — R8's swizzle strands
// heavy blocks alone on their CU for the tail (163->200 regression). Keeps
// stride-68 LDS, exp2 softmax, causal-skip. New: per-tile padAny flag (skips
// pad masking on all-ones masks), v_perm-based V transpose.
#define QT 128
#define KT 64
#define LDP 68    // Q/P row stride: 34 dwords -> conflict-free
#define LDPV 68   // Vs row stride

#define LOG2E 1.4426950408889634f

__global__ __launch_bounds__(256, 4) void attn_k(
    const u16* __restrict__ Q, const u16* __restrict__ K,
    const u16* __restrict__ V, const int* __restrict__ mask,
    u16* __restrict__ AO)
{
    __shared__ alignas(16) u16 QPs[QT * LDP];   // 17408 B: Q tile, then P tile
    __shared__ alignas(16) u16 Ks[KT * LDP];    //  8704 B
    __shared__ alignas(16) u16 Vs[HDD * LDPV];  //  8704 B  [hd][kpos]
    __shared__ float padf[KT];                  //   256 B
    __shared__ int padAny;

    const int tid = threadIdx.x, lane = tid & 63, w = tid >> 6;
    const int quad = lane >> 4, l15 = lane & 15;
    const int qt = (int)(gridDim.x - 1 - blockIdx.x);   // heavy tiles first
    const int bh = blockIdx.y;                          // R6 layout: CU's blocks same qt
    const int b = bh >> 4, h = bh & 15;
    const int q0 = qt * QT;
    const size_t hoff = (size_t)bh * SS * HDD;
    const u16* Qh = Q + hoff;
    const u16* Kh = K + hoff;
    const u16* Vh = V + hoff;

    // stage Q tile, then preload this wave's B-fragments into registers
    for (int c = tid; c < QT * 8; c += 256) {
        const int row = c >> 3, cc = c & 7;
        *(uint4*)&QPs[row * LDP + cc * 8] = *(const uint4*)&Qh[(size_t)(q0 + row) * HDD + cc * 8];
    }
    __syncthreads();
    bf16x8 bQ[2][2];
    #pragma unroll
    for (int j = 0; j < 2; ++j)
        #pragma unroll
        for (int ks = 0; ks < 2; ++ks)
            bQ[j][ks] = *(const bf16x8*)&QPs[(w * 32 + j * 16 + l15) * LDP + ks * 32 + quad * 8];
    // QPs rows w*32..w*32+31 are wave-private from here on.

    float m_run[2] = { -1e30f, -1e30f };
    float l_run[2] = { 0.f, 0.f };     // per-quad partials
    f32x4 o[4][2];
    #pragma unroll
    for (int i = 0; i < 4; ++i)
        #pragma unroll
        for (int j = 0; j < 2; ++j) o[i][j] = (f32x4)(0.0f);

    const int nkt = (q0 + QT) / KT;
    const float scale2 = 0.125f * LOG2E;   // HD^-0.5 folded with log2(e)

    for (int kt = 0; kt < nkt; ++kt) {
        const int kt0 = kt * KT;
        __syncthreads();   // prior iter's Ks/Vs reads complete

        if (tid < 128) {
            // Ks [kpos][hd]: 512 uint4 / 128 threads (direct, spill-free)
            #pragma unroll
            for (int it = 0; it < 4; ++it) {
                const int c = tid + it * 128;
                const int row = c >> 3, cc = c & 7;
                *(uint4*)&Ks[row * LDP + cc * 8] = *(const uint4*)&Kh[(size_t)(kt0 + row) * HDD + cc * 8];
            }
        } else {
            // Vs [hd][kpos]: transpose via v_perm (16 perms vs ~64 extracts)
            const int t = tid - 128;
            const int kq = t >> 3;
            const int c0 = (t & 7) * 8;
            uint4 r0 = *(const uint4*)&Vh[(size_t)(kt0 + kq * 4 + 0) * HDD + c0];
            uint4 r1 = *(const uint4*)&Vh[(size_t)(kt0 + kq * 4 + 1) * HDD + c0];
            uint4 r2 = *(const uint4*)&Vh[(size_t)(kt0 + kq * 4 + 2) * HDD + c0];
            uint4 r3 = *(const uint4*)&Vh[(size_t)(kt0 + kq * 4 + 3) * HDD + c0];
            const unsigned* d0 = (const unsigned*)&r0;
            const unsigned* d1 = (const unsigned*)&r1;
            const unsigned* d2 = (const unsigned*)&r2;
            const unsigned* d3 = (const unsigned*)&r3;
            #pragma unroll
            for (int tt = 0; tt < 4; ++tt) {
                uint2 lo, hi;
                lo.x = __builtin_amdgcn_perm(d1[tt], d0[tt], 0x05040100u); // (r0[2t],r1[2t])
                lo.y = __builtin_amdgcn_perm(d3[tt], d2[tt], 0x05040100u); // (r2[2t],r3[2t])
                hi.x = __builtin_amdgcn_perm(d1[tt], d0[tt], 0x07060302u); // (r0[2t+1],r1[2t+1])
                hi.y = __builtin_amdgcn_perm(d3[tt], d2[tt], 0x07060302u);
                *(uint2*)&Vs[(c0 + 2 * tt + 0) * LDPV + kq * 4] = lo;
                *(uint2*)&Vs[(c0 + 2 * tt + 1) * LDPV + kq * 4] = hi;
            }
        }
        if (tid < 64) {
            const int mv = mask[b * SS + kt0 + tid];
            padf[tid] = (mv == 0) ? 1.0f : 0.0f;
            const unsigned long long bm = __ballot(mv == 0);
            if (tid == 0) padAny = (bm != 0ull) ? 1 : 0;
        }
        __syncthreads();

        // S^T = K Q^T : C[kpos = i*16+quad*4+r][qrow = w*32+j*16+l15]
        f32x4 sc[4][2];
        #pragma unroll
        for (int i = 0; i < 4; ++i)
            #pragma unroll
            for (int j = 0; j < 2; ++j) sc[i][j] = (f32x4)(0.0f);
        #pragma unroll
        for (int ks = 0; ks < 2; ++ks) {
            bf16x8 aK[4];
            #pragma unroll
            for (int i = 0; i < 4; ++i)
                aK[i] = *(const bf16x8*)&Ks[(i * 16 + l15) * LDP + ks * 32 + quad * 8];
            #pragma unroll
            for (int i = 0; i < 4; ++i)
                #pragma unroll
                for (int j = 0; j < 2; ++j)
                    sc[i][j] = __builtin_amdgcn_mfma_f32_16x16x32_bf16(aK[i], bQ[j][ks], sc[i][j], 0, 0, 0);
        }

        const int sAny = padAny;   // block-uniform
        float pf[4][4];
        if (sAny) {
            #pragma unroll
            for (int i = 0; i < 4; ++i)
                #pragma unroll
                for (int r = 0; r < 4; ++r)
                    pf[i][r] = padf[i * 16 + quad * 4 + r];
        }

        #pragma unroll
        for (int j = 0; j < 2; ++j) {
            const int qrow = q0 + w * 32 + j * 16 + l15;
            const bool needC = (kt0 + KT - 1) > (q0 + w * 32 + j * 16);  // wave-uniform
            float mx = -1e9f;
            if (needC) {
                if (sAny) {
                    #pragma unroll
                    for (int i = 0; i < 4; ++i)
                        #pragma unroll
                        for (int r = 0; r < 4; ++r) {
                            const int kpg = kt0 + i * 16 + quad * 4 + r;
                            float s = sc[i][j][r] * scale2;
                            s = ((kpg > qrow) || (pf[i][r] != 0.f)) ? -1e9f : s;
                            sc[i][j][r] = s; mx = fmaxf(mx, s);
                        }
                } else {
                    #pragma unroll
                    for (int i = 0; i < 4; ++i)
                        #pragma unroll
                        for (int r = 0; r < 4; ++r) {
                            const int kpg = kt0 + i * 16 + quad * 4 + r;
                            float s = sc[i][j][r] * scale2;
                            s = (kpg > qrow) ? -1e9f : s;
                            sc[i][j][r] = s; mx = fmaxf(mx, s);
                        }
                }
            } else {
                if (sAny) {
                    #pragma unroll
                    for (int i = 0; i < 4; ++i)
                        #pragma unroll
                        for (int r = 0; r < 4; ++r) {
                            float s = sc[i][j][r] * scale2;
                            s = (pf[i][r] != 0.f) ? -1e9f : s;
                            sc[i][j][r] = s; mx = fmaxf(mx, s);
                        }
                } else {
                    // fast path: no causal, no pad (dominant for all-ones mask)
                    #pragma unroll
                    for (int i = 0; i < 4; ++i)
                        #pragma unroll
                        for (int r = 0; r < 4; ++r) {
                            const float s = sc[i][j][r] * scale2;
                            sc[i][j][r] = s; mx = fmaxf(mx, s);
                        }
                }
            }
            mx = fmaxf(mx, __shfl_xor(mx, 16, 64));
            mx = fmaxf(mx, __shfl_xor(mx, 32, 64));
            const float nm = fmaxf(m_run[j], mx);
            const float alpha = __builtin_exp2f(m_run[j] - nm);
            m_run[j] = nm;
            float rs = 0.f;
            #pragma unroll
            for (int i = 0; i < 4; ++i) {
                float p0 = __builtin_exp2f(sc[i][j][0] - nm);
                float p1 = __builtin_exp2f(sc[i][j][1] - nm);
                float p2 = __builtin_exp2f(sc[i][j][2] - nm);
                float p3 = __builtin_exp2f(sc[i][j][3] - nm);
                rs += (p0 + p1) + (p2 + p3);
                *(ushort4*)&QPs[(w * 32 + j * 16 + l15) * LDP + i * 16 + quad * 4] = pk4(p0, p1, p2, p3);
            }
            l_run[j] = l_run[j] * alpha + rs;
            #pragma unroll
            for (int i = 0; i < 4; ++i)
                #pragma unroll
                for (int r = 0; r < 4; ++r) o[i][j][r] *= alpha;
        }
        // same-wave LDS RAW (QPs writes -> bP reads)
        asm volatile("s_waitcnt lgkmcnt(0)" ::: "memory");

        // O^T += V^T P^T : A = Vs[hd][kpos], B = QPs[qrow][kpos]
        #pragma unroll
        for (int ks = 0; ks < 2; ++ks) {
            bf16x8 aV[4], bP[2];
            #pragma unroll
            for (int i = 0; i < 4; ++i)
                aV[i] = *(const bf16x8*)&Vs[(i * 16 + l15) * LDPV + ks * 32 + quad * 8];
            #pragma unroll
            for (int j = 0; j < 2; ++j)
                bP[j] = *(const bf16x8*)&QPs[(w * 32 + j * 16 + l15) * LDP + ks * 32 + quad * 8];
            #pragma unroll
            for (int i = 0; i < 4; ++i)
                #pragma unroll
                for (int j = 0; j < 2; ++j)
                    o[i][j] = __builtin_amdgcn_mfma_f32_16x16x32_bf16(aV[i], bP[j], o[i][j], 0, 0, 0);
        }
    }

    // final l reduction across quads, then store O^T -> AO [B,S,H*HD] (bf16)
    #pragma unroll
    for (int j = 0; j < 2; ++j) {
        float l = l_run[j];
        l += __shfl_xor(l, 16, 64);
        l += __shfl_xor(l, 32, 64);
        const float inv = (l > 0.f) ? (1.f / l) : 0.f;
        const int s = q0 + w * 32 + j * 16 + l15;
        const size_t rb = ((size_t)(b * SS + s)) * DD + h * HDD;
        #pragma unroll
        for (int i = 0; i < 4; ++i)
            *(ushort4*)&AO[rb + i * 16 + quad * 4] =
                pk4(o[i][j][0] * inv, o[i][j][1] * inv, o[i][j][2] * inv, o[i][j][3] * inv);
    }
}

extern "C" void kernel_launch(void* const* d_in, const int* in_sizes, int n_in,
                              void* d_out, int out_size, void* d_ws, size_t ws_size,
                              hipStream_t stream)
{
    const float* x  = (const float*)d_in[0];
    const int* mask = (const int*)d_in[1];
    const float* Wq = (const float*)d_in[2];
    const float* bq = (const float*)d_in[3];
    const float* Wk = (const float*)d_in[4];
    const float* bk = (const float*)d_in[5];
    const float* Wv = (const float*)d_in[6];
    const float* bv = (const float*)d_in[7];
    const float* Wo = (const float*)d_in[8];
    const float* bo = (const float*)d_in[9];
    float* out = (float*)d_out;

    u16* ws = (u16*)d_ws;
    const size_t NE = (size_t)MM * DD;
    if (ws_size < 4 * NE * sizeof(u16)) return;

    u16* Qb = ws;
    u16* Kb = ws + NE;
    u16* Vb = ws + 2 * NE;
    u16* Ab = ws + 3 * NE;   // x_bf16 first, then attention output (sequential reuse)

    dim3 blk(256);
    cvt_k<<<dim3(NE / 2048), blk, 0, stream>>>(x, Ab);
    gemm_qkv_k<<<dim3(MM / 128, DD / 128, 3), blk, 0, stream>>>(
        Ab, Wq, bq, Wk, bk, Wv, bv, Qb, Kb, Vb);
    attn_k<<<dim3(SS / QT, BB * HH), blk, 0, stream>>>(Qb, Kb, Vb, mask, Ab);
    gemm_out_k<<<dim3(MM / 128, DD / 128), blk, 0, stream>>>(Ab, Wo, bo, out);
}

// Round 10
// 348.474 us; speedup vs baseline: 1.2504x; 1.2504x over previous
//
#include <hip/hip_runtime.h>
#include <hip/hip_bf16.h>

typedef unsigned short u16;
typedef float f32x4 __attribute__((ext_vector_type(4)));
typedef __bf16 bf16x8 __attribute__((ext_vector_type(8)));

#define BB 4
#define SS 2048
#define DD 1024
#define HH 16
#define HDD 64
#define MM (BB*SS)   // 8192

__device__ __forceinline__ u16 f2bf(float f){
    union { float f; unsigned int i; } v; v.f = f;
    unsigned int i = v.i;
    return (u16)((i + 0x7FFFu + ((i >> 16) & 1u)) >> 16);
}
__device__ __forceinline__ ushort2 pk2(float a, float b){
    union { __hip_bfloat162 h; ushort2 u; } v;
    float2 t; t.x = a; t.y = b;
    v.h = __float22bfloat162_rn(t);
    return v.u;
}
__device__ __forceinline__ ushort4 pk4(float a, float b, float c, float d){
    ushort2 lo = pk2(a, b), hi = pk2(c, d);
    ushort4 r; r.x = lo.x; r.y = lo.y; r.z = hi.x; r.w = hi.y;
    return r;
}
__device__ __forceinline__ void gl2lds16(const void* g, void* l){
    __builtin_amdgcn_global_load_lds(
        (const __attribute__((address_space(1))) void*)g,
        (__attribute__((address_space(3))) void*)l, 16, 0, 0);
}

// ---------------- x fp32 -> bf16 pre-convert ----------------
__global__ __launch_bounds__(256) void cvt_k(const float* __restrict__ src,
                                             u16* __restrict__ dst)
{
    const size_t i = ((size_t)blockIdx.x * 256 + threadIdx.x) * 8;
    const float4 a = *(const float4*)&src[i];
    const float4 b = *(const float4*)&src[i + 4];
    ushort4 lo = pk4(a.x, a.y, a.z, a.w);
    ushort4 hi = pk4(b.x, b.y, b.z, b.w);
    uint4 o;
    o.x = (unsigned)lo.x | ((unsigned)lo.y << 16);
    o.y = (unsigned)lo.z | ((unsigned)lo.w << 16);
    o.z = (unsigned)hi.x | ((unsigned)hi.y << 16);
    o.w = (unsigned)hi.z | ((unsigned)hi.w << 16);
    *(uint4*)&dst[i] = o;
}

// ---------------- GEMM core: C[128,128] tile of A_bf16[M,K] @ W_f32[N,K]^T ----------------
__device__ __forceinline__ void gemm_core(const u16* __restrict__ A,
                                          const float* __restrict__ W,
                                          f32x4 (&acc)[4][4],
                                          u16* At, u16* Bt,
                                          int m0, int n0, int tid)
{
    const int lane = tid & 63, w = tid >> 6;
    const int quad = lane >> 4, l15 = lane & 15;
    const int wm = w >> 1, wn = w & 1;
    const int arow = lane >> 2;          // 0..15 within chunk
    const int acol = (lane & 3) * 8;     // element offset (16B)

    for (int k0 = 0; k0 < DD; k0 += 32) {
        __syncthreads();
        // A: async direct-to-LDS, chunk ch = 16 rows x 32 elems, lane-linear
        #pragma unroll
        for (int c = 0; c < 2; ++c) {
            const int ch = w * 2 + c;     // wave-uniform
            gl2lds16(&A[(size_t)(m0 + ch * 16 + arow) * DD + k0 + acol], &At[ch * 512]);
        }
        // W: explicit + convert
        #pragma unroll
        for (int it = 0; it < 2; ++it) {
            const int c = tid + it * 256;
            const int row = c >> 2, cc = (c & 3) * 8;
            const size_t woff = (size_t)(n0 + row) * DD + k0 + cc;
            const float4 u0 = *(const float4*)&W[woff];
            const float4 u1 = *(const float4*)&W[woff + 4];
            ushort4 lo = pk4(u0.x, u0.y, u0.z, u0.w);
            ushort4 hi = pk4(u1.x, u1.y, u1.z, u1.w);
            uint4 o;
            o.x = (unsigned)lo.x | ((unsigned)lo.y << 16);
            o.y = (unsigned)lo.z | ((unsigned)lo.w << 16);
            o.z = (unsigned)hi.x | ((unsigned)hi.y << 16);
            o.w = (unsigned)hi.z | ((unsigned)hi.w << 16);
            *(uint4*)&Bt[row * 32 + cc] = o;
        }
        __syncthreads();
        bf16x8 af[4], bfr[4];
        #pragma unroll
        for (int i = 0; i < 4; ++i)
            af[i] = *(const bf16x8*)&At[(wm * 64 + i * 16 + l15) * 32 + quad * 8];
        #pragma unroll
        for (int j = 0; j < 4; ++j)
            bfr[j] = *(const bf16x8*)&Bt[(wn * 64 + j * 16 + l15) * 32 + quad * 8];
        #pragma unroll
        for (int i = 0; i < 4; ++i)
            #pragma unroll
            for (int j = 0; j < 4; ++j)
                acc[i][j] = __builtin_amdgcn_mfma_f32_16x16x32_bf16(af[i], bfr[j], acc[i][j], 0, 0, 0);
    }
}

// QKV projection: z selects q/k/v; output scattered to [B,H,S,HD] (bf16)
__global__ __launch_bounds__(256, 4) void gemm_qkv_k(
    const u16* __restrict__ x,
    const float* __restrict__ Wq, const float* __restrict__ bq,
    const float* __restrict__ Wk, const float* __restrict__ bk,
    const float* __restrict__ Wv, const float* __restrict__ bv,
    u16* __restrict__ Q, u16* __restrict__ K, u16* __restrict__ V)
{
    __shared__ alignas(16) u16 At[128 * 32];
    __shared__ alignas(16) u16 Bt[128 * 32];
    const int tid = threadIdx.x, lane = tid & 63, w = tid >> 6;
    const int quad = lane >> 4, l15 = lane & 15;
    const int wm = w >> 1, wn = w & 1;
    const int z = blockIdx.z;
    const float* Wm = z == 0 ? Wq : (z == 1 ? Wk : Wv);
    const float* bias = z == 0 ? bq : (z == 1 ? bk : bv);
    u16* Out = z == 0 ? Q : (z == 1 ? K : V);
    const int m0 = blockIdx.x * 128, n0 = blockIdx.y * 128;

    f32x4 acc[4][4];
    #pragma unroll
    for (int i = 0; i < 4; ++i)
        #pragma unroll
        for (int j = 0; j < 4; ++j) acc[i][j] = (f32x4)(0.0f);

    gemm_core(x, Wm, acc, At, Bt, m0, n0, tid);

    float bs[4];
    #pragma unroll
    for (int j = 0; j < 4; ++j) bs[j] = bias[n0 + wn * 64 + j * 16 + l15];

    const int b = m0 / SS;
    const int h = (n0 + wn * 64) / HDD;
    const size_t base = ((size_t)(b * HH + h)) * SS * HDD;
    #pragma unroll
    for (int i = 0; i < 4; ++i) {
        #pragma unroll
        for (int r = 0; r < 4; ++r) {
            const int s = (m0 % SS) + wm * 64 + i * 16 + quad * 4 + r;
            #pragma unroll
            for (int j = 0; j < 4; ++j) {
                const int hd = j * 16 + l15;
                Out[base + (size_t)s * HDD + hd] = f2bf(acc[i][j][r] + bs[j]);
            }
        }
    }
}

// Output projection: A bf16 [M,K], Wo fp32, out fp32 [M,N]
__global__ __launch_bounds__(256, 4) void gemm_out_k(
    const u16* __restrict__ A, const float* __restrict__ Wo,
    const float* __restrict__ bo, float* __restrict__ Out)
{
    __shared__ alignas(16) u16 At[128 * 32];
    __shared__ alignas(16) u16 Bt[128 * 32];
    const int tid = threadIdx.x, lane = tid & 63, w = tid >> 6;
    const int quad = lane >> 4, l15 = lane & 15;
    const int wm = w >> 1, wn = w & 1;
    const int m0 = blockIdx.x * 128, n0 = blockIdx.y * 128;

    f32x4 acc[4][4];
    #pragma unroll
    for (int i = 0; i < 4; ++i)
        #pragma unroll
        for (int j = 0; j < 4; ++j) acc[i][j] = (f32x4)(0.0f);

    gemm_core(A, Wo, acc, At, Bt, m0, n0, tid);

    float bs[4];
    #pragma unroll
    for (int j = 0; j < 4; ++j) bs[j] = bo[n0 + wn * 64 + j * 16 + l15];

    #pragma unroll
    for (int i = 0; i < 4; ++i) {
        #pragma unroll
        for (int r = 0; r < 4; ++r) {
            const int m = m0 + wm * 64 + i * 16 + quad * 4 + r;
            #pragma unroll
            for (int j = 0; j < 4; ++j) {
                const int n = n0 + wn * 64 + j * 16 + l15;
                Out[(size_t)m * DD + n] = acc[i][j][r] + bs[j];
            }
        }
    }
}

// ---------------- Flash attention, S^T/O^T, QT=256 x 8 waves ----------------
// R10: LDS geometry reverted to R6-proven 72/66 (LDP=68 broke 16B alignment of
// every b128 access on odd rows — the R8/R9 regression). Structural: QT=256,
// 512 threads (per-wave code unchanged; each wave owns 32 q-rows) -> k-iters,
// staging bytes, and barriers per MFMA all halve. Grid (x=bh, y=8) with
// qt = y<4 ? 7-y : y-4: CU gets blocks c,c+256 = same bh (L2 K/V sharing),
// qt pairs (7,0)(6,1)(5,2)(4,3) -> uniform 36 k-iters/CU.
#define QT 256
#define KT 64
#define LDP 72    // 144B = 9*16B: every row 16B-aligned
#define LDPV 66

#define LOG2E 1.4426950408889634f

__global__ __launch_bounds__(512, 2) void attn_k(
    const u16* __restrict__ Q, const u16* __restrict__ K,
    const u16* __restrict__ V, const int* __restrict__ mask,
    u16* __restrict__ AO)
{
    __shared__ alignas(16) u16 QPs[QT * LDP];   // 36864 B: Q tile, then P tile
    __shared__ alignas(16) u16 Ks[KT * LDP];    //  9216 B
    __shared__ alignas(16) u16 Vs[HDD * LDPV];  //  8448 B  [hd][kpos]
    __shared__ float padf[KT];                  //   256 B
    // total 54784 B -> 2 blocks/CU x 8 waves = 16 waves/CU

    const int tid = threadIdx.x, lane = tid & 63, w = tid >> 6;   // w in 0..7
    const int quad = lane >> 4, l15 = lane & 15;
    const int bh = blockIdx.x;
    const int y = blockIdx.y;
    const int qt = (y < 4) ? (7 - y) : (y - 4);   // pairs (7,0)(6,1)(5,2)(4,3)
    const int b = bh >> 4, h = bh & 15;
    const int q0 = qt * QT;
    const size_t hoff = (size_t)bh * SS * HDD;
    const u16* Qh = Q + hoff;
    const u16* Kh = K + hoff;
    const u16* Vh = V + hoff;

    // stage Q tile (256 rows x 8 chunks = 2048 uint4 / 512 threads = 4 each)
    for (int c = tid; c < QT * 8; c += 512) {
        const int row = c >> 3, cc = c & 7;
        *(uint4*)&QPs[row * LDP + cc * 8] = *(const uint4*)&Qh[(size_t)(q0 + row) * HDD + cc * 8];
    }
    __syncthreads();
    bf16x8 bQ[2][2];
    #pragma unroll
    for (int j = 0; j < 2; ++j)
        #pragma unroll
        for (int ks = 0; ks < 2; ++ks)
            bQ[j][ks] = *(const bf16x8*)&QPs[(w * 32 + j * 16 + l15) * LDP + ks * 32 + quad * 8];
    // QPs rows w*32..w*32+31 are wave-private from here on.

    float m_run[2] = { -1e30f, -1e30f };
    float l_run[2] = { 0.f, 0.f };     // per-quad partials
    f32x4 o[4][2];
    #pragma unroll
    for (int i = 0; i < 4; ++i)
        #pragma unroll
        for (int j = 0; j < 2; ++j) o[i][j] = (f32x4)(0.0f);

    const int nkt = (q0 + QT) / KT;
    const float scale2 = 0.125f * LOG2E;   // HD^-0.5 folded with log2(e)

    for (int kt = 0; kt < nkt; ++kt) {
        const int kt0 = kt * KT;
        __syncthreads();   // prior iter's Ks/Vs reads complete

        if (tid < 256) {
            // Ks [kpos][hd]: 512 uint4 / 256 threads = 2 each
            #pragma unroll
            for (int it = 0; it < 2; ++it) {
                const int c = tid + it * 256;
                const int row = c >> 3, cc = c & 7;
                *(uint4*)&Ks[row * LDP + cc * 8] = *(const uint4*)&Kh[(size_t)(kt0 + row) * HDD + cc * 8];
            }
        } else if (tid < 384) {
            // Vs [hd][kpos]: R6-proven pack-4 transpose (128 threads x 4 rows)
            const int t = tid - 256;
            const int kq = t >> 3;
            const int c0 = (t & 7) * 8;
            uint4 r0 = *(const uint4*)&Vh[(size_t)(kt0 + kq * 4 + 0) * HDD + c0];
            uint4 r1 = *(const uint4*)&Vh[(size_t)(kt0 + kq * 4 + 1) * HDD + c0];
            uint4 r2 = *(const uint4*)&Vh[(size_t)(kt0 + kq * 4 + 2) * HDD + c0];
            uint4 r3 = *(const uint4*)&Vh[(size_t)(kt0 + kq * 4 + 3) * HDD + c0];
            const u16* e0 = (const u16*)&r0;
            const u16* e1 = (const u16*)&r1;
            const u16* e2 = (const u16*)&r2;
            const u16* e3 = (const u16*)&r3;
            #pragma unroll
            for (int e = 0; e < 8; ++e) {
                ushort4 pkv; pkv.x = e0[e]; pkv.y = e1[e]; pkv.z = e2[e]; pkv.w = e3[e];
                *(ushort4*)&Vs[(c0 + e) * LDPV + kq * 4] = pkv;
            }
        } else if (tid < 448) {
            const int t = tid - 384;
            padf[t] = (mask[b * SS + kt0 + t] == 0) ? 1.0f : 0.0f;
        }
        __syncthreads();

        // S^T = K Q^T : C[kpos = i*16+quad*4+r][qrow = w*32+j*16+l15]
        f32x4 sc[4][2];
        #pragma unroll
        for (int i = 0; i < 4; ++i)
            #pragma unroll
            for (int j = 0; j < 2; ++j) sc[i][j] = (f32x4)(0.0f);
        #pragma unroll
        for (int ks = 0; ks < 2; ++ks) {
            bf16x8 aK[4];
            #pragma unroll
            for (int i = 0; i < 4; ++i)
                aK[i] = *(const bf16x8*)&Ks[(i * 16 + l15) * LDP + ks * 32 + quad * 8];
            #pragma unroll
            for (int i = 0; i < 4; ++i)
                #pragma unroll
                for (int j = 0; j < 2; ++j)
                    sc[i][j] = __builtin_amdgcn_mfma_f32_16x16x32_bf16(aK[i], bQ[j][ks], sc[i][j], 0, 0, 0);
        }

        float pf[4][4];
        #pragma unroll
        for (int i = 0; i < 4; ++i)
            #pragma unroll
            for (int r = 0; r < 4; ++r)
                pf[i][r] = padf[i * 16 + quad * 4 + r];

        #pragma unroll
        for (int j = 0; j < 2; ++j) {
            const int qrow = q0 + w * 32 + j * 16 + l15;
            const bool needC = (kt0 + KT - 1) > (q0 + w * 32 + j * 16);  // wave-uniform
            float mx = -1e9f;
            if (needC) {
                #pragma unroll
                for (int i = 0; i < 4; ++i)
                    #pragma unroll
                    for (int r = 0; r < 4; ++r) {
                        const int kpg = kt0 + i * 16 + quad * 4 + r;
                        float s = sc[i][j][r] * scale2;
                        s = ((kpg > qrow) || (pf[i][r] != 0.f)) ? -1e9f : s;
                        sc[i][j][r] = s; mx = fmaxf(mx, s);
                    }
            } else {
                #pragma unroll
                for (int i = 0; i < 4; ++i)
                    #pragma unroll
                    for (int r = 0; r < 4; ++r) {
                        float s = sc[i][j][r] * scale2;
                        s = (pf[i][r] != 0.f) ? -1e9f : s;
                        sc[i][j][r] = s; mx = fmaxf(mx, s);
                    }
            }
            mx = fmaxf(mx, __shfl_xor(mx, 16, 64));
            mx = fmaxf(mx, __shfl_xor(mx, 32, 64));
            const float nm = fmaxf(m_run[j], mx);
            const float alpha = __builtin_exp2f(m_run[j] - nm);
            m_run[j] = nm;
            float rs = 0.f;
            #pragma unroll
            for (int i = 0; i < 4; ++i) {
                float p0 = __builtin_exp2f(sc[i][j][0] - nm);
                float p1 = __builtin_exp2f(sc[i][j][1] - nm);
                float p2 = __builtin_exp2f(sc[i][j][2] - nm);
                float p3 = __builtin_exp2f(sc[i][j][3] - nm);
                rs += (p0 + p1) + (p2 + p3);
                *(ushort4*)&QPs[(w * 32 + j * 16 + l15) * LDP + i * 16 + quad * 4] = pk4(p0, p1, p2, p3);
            }
            l_run[j] = l_run[j] * alpha + rs;
            #pragma unroll
            for (int i = 0; i < 4; ++i)
                #pragma unroll
                for (int r = 0; r < 4; ++r) o[i][j][r] *= alpha;
        }
        // same-wave LDS RAW (QPs writes -> bP reads)
        asm volatile("s_waitcnt lgkmcnt(0)" ::: "memory");

        // O^T += V^T P^T : A = Vs[hd][kpos], B = QPs[qrow][kpos]
        #pragma unroll
        for (int ks = 0; ks < 2; ++ks) {
            bf16x8 aV[4], bP[2];
            #pragma unroll
            for (int i = 0; i < 4; ++i)
                aV[i] = *(const bf16x8*)&Vs[(i * 16 + l15) * LDPV + ks * 32 + quad * 8];
            #pragma unroll
            for (int j = 0; j < 2; ++j)
                bP[j] = *(const bf16x8*)&QPs[(w * 32 + j * 16 + l15) * LDP + ks * 32 + quad * 8];
            #pragma unroll
            for (int i = 0; i < 4; ++i)
                #pragma unroll
                for (int j = 0; j < 2; ++j)
                    o[i][j] = __builtin_amdgcn_mfma_f32_16x16x32_bf16(aV[i], bP[j], o[i][j], 0, 0, 0);
        }
    }

    // final l reduction across quads, then store O^T -> AO [B,S,H*HD] (bf16)
    #pragma unroll
    for (int j = 0; j < 2; ++j) {
        float l = l_run[j];
        l += __shfl_xor(l, 16, 64);
        l += __shfl_xor(l, 32, 64);
        const float inv = (l > 0.f) ? (1.f / l) : 0.f;
        const int s = q0 + w * 32 + j * 16 + l15;
        const size_t rb = ((size_t)(b * SS + s)) * DD + h * HDD;
        #pragma unroll
        for (int i = 0; i < 4; ++i)
            *(ushort4*)&AO[rb + i * 16 + quad * 4] =
                pk4(o[i][j][0] * inv, o[i][j][1] * inv, o[i][j][2] * inv, o[i][j][3] * inv);
    }
}

extern "C" void kernel_launch(void* const* d_in, const int* in_sizes, int n_in,
                              void* d_out, int out_size, void* d_ws, size_t ws_size,
                              hipStream_t stream)
{
    const float* x  = (const float*)d_in[0];
    const int* mask = (const int*)d_in[1];
    const float* Wq = (const float*)d_in[2];
    const float* bq = (const float*)d_in[3];
    const float* Wk = (const float*)d_in[4];
    const float* bk = (const float*)d_in[5];
    const float* Wv = (const float*)d_in[6];
    const float* bv = (const float*)d_in[7];
    const float* Wo = (const float*)d_in[8];
    const float* bo = (const float*)d_in[9];
    float* out = (float*)d_out;

    u16* ws = (u16*)d_ws;
    const size_t NE = (size_t)MM * DD;
    if (ws_size < 4 * NE * sizeof(u16)) return;

    u16* Qb = ws;
    u16* Kb = ws + NE;
    u16* Vb = ws + 2 * NE;
    u16* Ab = ws + 3 * NE;   // x_bf16 first, then attention output (sequential reuse)

    dim3 blk(256);
    cvt_k<<<dim3(NE / 2048), blk, 0, stream>>>(x, Ab);
    gemm_qkv_k<<<dim3(MM / 128, DD / 128, 3), blk, 0, stream>>>(
        Ab, Wq, bq, Wk, bk, Wv, bv, Qb, Kb, Vb);
    attn_k<<<dim3(BB * HH, SS / QT), dim3(512), 0, stream>>>(Qb, Kb, Vb, mask, Ab);
    gemm_out_k<<<dim3(MM / 128, DD / 128), blk, 0, stream>>>(Ab, Wo, bo, out);
}